// Round 11
// baseline (790.282 us; speedup 1.0000x reference)
//
#include <hip/hip_runtime.h>

#define H  512
#define NN 10000
#define SS 20
#define VV 100000
#define EE 100000

typedef __bf16 bf16x8 __attribute__((ext_vector_type(8)));
typedef float  f32x4  __attribute__((ext_vector_type(4)));

__device__ __forceinline__ unsigned short f2bf(float f) {
  unsigned u = __builtin_bit_cast(unsigned, f);
  u += 0x7FFFu + ((u >> 16) & 1u);
  return (unsigned short)(u >> 16);
}
__device__ __forceinline__ float bflo(int x) {
  return __builtin_bit_cast(float, (unsigned)x << 16);
}
__device__ __forceinline__ float bfhi(int x) {
  return __builtin_bit_cast(float, (unsigned)x & 0xFFFF0000u);
}
__device__ __forceinline__ float sigm(float x) { return 1.f / (1.f + __expf(-x)); }

// bf16 packing (kept for out2_kernel staging)
__device__ __forceinline__ unsigned cpk(float lo, float hi) {
  unsigned r;
  asm("v_cvt_pk_bf16_f32 %0, %1, %2" : "=v"(r) : "v"(lo), "v"(hi));
  return r;
}
__device__ __forceinline__ void cvt_store8(unsigned short* dst, float4 a, float4 b) {
  int4 v;
  v.x = (int)cpk(a.x, a.y); v.y = (int)cpk(a.z, a.w);
  v.z = (int)cpk(b.x, b.y); v.w = (int)cpk(b.z, b.w);
  *(int4*)dst = v;
}

// 8 f32 -> 8 fp8 (OCP e4m3 on gfx950) packed in a uint2 (4 VALU ops).
__device__ __forceinline__ uint2 cvt8_fp8(float4 a, float4 b) {
  int x = __builtin_amdgcn_cvt_pk_fp8_f32(a.x, a.y, 0, false);
  x = __builtin_amdgcn_cvt_pk_fp8_f32(a.z, a.w, x, true);
  int y = __builtin_amdgcn_cvt_pk_fp8_f32(b.x, b.y, 0, false);
  y = __builtin_amdgcn_cvt_pk_fp8_f32(b.z, b.w, y, true);
  uint2 r; r.x = (unsigned)x; r.y = (unsigned)y; return r;
}

// non-draining barrier: publish LDS writes, do NOT drain vmcnt (in-flight
// global loads legally span the barrier).
__device__ __forceinline__ void pub_barrier() {
  asm volatile("s_waitcnt lgkmcnt(0)\n\ts_barrier" ::: "memory");
}

// ---------------- fused gather + GEMM + GRU scan (persistent-B, fp8) --------
// R10 (599us): conflict-free fp8 swizzle f(ar)=(ar>>1)&7 (verified: 1.7e8->0)
// + 3 waves/SIMD. Remaining anomaly: WRITE 120MB = ~100MB scratch spill.
// R11: spill is EPILOGUE-pressure (barr 64 + acc 40 + 24 f32 pf live through
// the 20-step scan > 168 cap). Fix: keep pipeline state PACKED (pk, 6 regs)
// instead of f32 (24) across the epilogue by cvt-ing one body early:
//   body(kc): ds_write pk(kc+1) ; cvt pa/pb(kc+2)->pk ; issue a(kc+3) ;
//             MFMA(kc) ; issue b(kc+3) ; barrier     [issues skipped kc=7]
// Data path: load(c) body c-3 -> cvt(c) body c-2 -> store(c) body c-1 ->
// MFMA(c) body c. cvt inputs have ~1 body latency cover (same as R10's
// store path). Chunk c -> buffer c&3; write->1 barrier->read->3->rewrite.
// Post-epilogue: issue chunk 2 of the new ng (covered by epilogue tail).
// Epilogue peak ~125 regs < 168 -> no spill.
// Grid 16cg x 48sb = 768 = 3/CU, __launch_bounds__(256,3).
// XCD swizzle (bijective, all 16 cg of an sb on one XCD): hwid = by*16+bx;
// j = hwid>>3; cg = j&15, sb = (hwid&7)*6 + (j>>4).
__launch_bounds__(256, 3)
__global__ void gru_fused(const float* __restrict__ emb,
                          const float* __restrict__ W_ir,
                          const float* __restrict__ W_iz,
                          const float* __restrict__ b_ir,
                          const float* __restrict__ b_iz,
                          const int* __restrict__ walk,
                          unsigned short* __restrict__ hnb) {
  __shared__ __align__(16) unsigned char As[4][80 * 64];  // fp8 tiles, 64B rows
  __shared__ unsigned short hout[2][4][32];   // [ng&1][node][channel-local]

  const int tid = threadIdx.x;
  const int w = tid >> 6, lane = tid & 63;
  const int r = lane & 15, q = lane >> 4;

  // XCD-aware remap (see header comment)
  const int hwid = blockIdx.y * 16 + blockIdx.x;
  const int j = hwid >> 3;
  const int cg = j & 15;
  const int sb = (hwid & 7) * 6 + (j >> 4);
  const int c0 = cg * 32;

  // ---- persistent B fragments: 2 tiles x 16 k-steps x 8 fp8 = 64 VGPRs ----
  const int ly = r & 1;                       // layer of this lane's columns
  const int cch = c0 + 8 * w + (r >> 1);      // channel of this lane's columns
  long long barr[2][16];
  float bias2[2];
  #pragma unroll
  for (int t = 0; t < 2; ++t) {               // t: 0 = h (W_ir), 1 = z (W_iz)
    const float* wrow = (t ? W_iz : W_ir) + (long)ly * H * H + (long)cch * H;
    #pragma unroll
    for (int u = 0; u < 16; ++u) {
      const float* s = wrow + u * 32 + q * 8;
      uint2 v = cvt8_fp8(*(const float4*)s, *(const float4*)(s + 4));
      barr[t][u] = __builtin_bit_cast(long long, v);
    }
    bias2[t] = (t ? b_iz : b_ir)[ly * H + cch];
  }

  // ---- A staging roles: thread -> rows {row0, +32, +64 (tid<128)} ----------
  // LMAP(m)=20*((m>>2)&3)+4*(m>>4)+(m&3): LMAP(m+32)=+8, LMAP(m+64)=+16.
  // SWZ(m)=m*64+((g0^((m>>1)&7))*8):      SWZ(m+32)=+2048, SWZ(m+64)=+4096.
  const int row0 = tid >> 3, g0 = tid & 7;
  const bool has2 = (tid < 128);              // wave-uniform (waves 0,1)
  const int L0 = 20 * ((row0 >> 2) & 3) + 4 * (row0 >> 4) + (row0 & 3);
  const int sw0 = row0 * 64 + ((g0 ^ ((row0 >> 1) & 7)) * 8);

  const int ngA = (2500 * sb) / 48;
  const int ngB = (2500 * (sb + 1)) / 48;

  int cur0, cur1, cur2;
  {
    const int* wp = walk + ngA * 80 + L0;
    int v0 = wp[0];  v0 = ((unsigned)v0 < VV) ? v0 : 0;
    int v1 = wp[8];  v1 = ((unsigned)v1 < VV) ? v1 : 0;
    int v2 = has2 ? wp[16] : 0; v2 = ((unsigned)v2 < VV) ? v2 : 0;
    cur0 = v0 * H; cur1 = v1 * H; cur2 = v2 * H;
  }

  // pipeline state: packed pending-store chunk (6 regs) + f32 chunk in flight
  uint2 pk0, pk1, pk2 = {0, 0};
  float4 pa0, pb0, pa1, pb1, pa2 = {0,0,0,0}, pb2 = {0,0,0,0};

  // ---- prologue: stage ch0; pk = cvt(ch1); issue ch2 -----------------------
  {
    const float* s0 = emb + cur0 + g0 * 8;
    const float* s1 = emb + cur1 + g0 * 8;
    const float* s2 = emb + cur2 + g0 * 8;
    float4 a0 = *(const float4*)s0, b0 = *(const float4*)(s0 + 4);
    float4 a1 = *(const float4*)s1, b1 = *(const float4*)(s1 + 4);
    float4 a2 = {0,0,0,0}, b2 = {0,0,0,0};
    if (has2) { a2 = *(const float4*)s2; b2 = *(const float4*)(s2 + 4); }
    *(uint2*)(&As[0][0] + sw0)        = cvt8_fp8(a0, b0);
    *(uint2*)(&As[0][0] + sw0 + 2048) = cvt8_fp8(a1, b1);
    if (has2) *(uint2*)(&As[0][0] + sw0 + 4096) = cvt8_fp8(a2, b2);
    // pk = chunk 1
    a0 = *(const float4*)(s0 + 64); b0 = *(const float4*)(s0 + 68);
    a1 = *(const float4*)(s1 + 64); b1 = *(const float4*)(s1 + 68);
    if (has2) { a2 = *(const float4*)(s2 + 64); b2 = *(const float4*)(s2 + 68); }
    pk0 = cvt8_fp8(a0, b0);
    pk1 = cvt8_fp8(a1, b1);
    if (has2) pk2 = cvt8_fp8(a2, b2);
    // issue chunk 2
    pa0 = *(const float4*)(s0 + 128); pb0 = *(const float4*)(s0 + 132);
    pa1 = *(const float4*)(s1 + 128); pb1 = *(const float4*)(s1 + 132);
    if (has2) { pa2 = *(const float4*)(s2 + 128); pb2 = *(const float4*)(s2 + 132); }
  }
  pub_barrier();

  f32x4 acc[5][2];
  const f32x4 fz = {0.f, 0.f, 0.f, 0.f};

  for (int ng = ngA; ng < ngB; ++ng) {
    #pragma unroll
    for (int mt = 0; mt < 5; ++mt)
      #pragma unroll
      for (int t = 0; t < 2; ++t) acc[mt][t] = fz;

    const int ngn = (ng + 1 < ngB) ? ng + 1 : ng;   // clamped walk prefetch
    int nxt0, nxt1, nxt2;
    {
      const int* wp = walk + ngn * 80 + L0;
      int n0 = wp[0];  n0 = ((unsigned)n0 < VV) ? n0 : 0;
      int n1 = wp[8];  n1 = ((unsigned)n1 < VV) ? n1 : 0;
      int n2 = has2 ? wp[16] : 0; n2 = ((unsigned)n2 < VV) ? n2 : 0;
      nxt0 = n0 * H; nxt1 = n1 * H; nxt2 = n2 * H;
    }

    #pragma unroll
    for (int kc = 0; kc < 8; ++kc) {
      // (a) store packed chunk kc+1 into buffer (kc+1)&3
      {
        unsigned char* An = &As[(kc + 1) & 3][0];
        *(uint2*)(An + sw0)        = pk0;
        *(uint2*)(An + sw0 + 2048) = pk1;
        if (has2) *(uint2*)(An + sw0 + 4096) = pk2;
      }
      // (b) cvt chunk kc+2 (f32 issued last body / prologue) -> pk
      pk0 = cvt8_fp8(pa0, pb0);
      pk1 = cvt8_fp8(pa1, pb1);
      if (has2) pk2 = cvt8_fp8(pa2, pb2);
      // (c) issue a-half loads chunk kc+3
      if (kc < 7) {
        const int cix = kc + 3;                     // 3..9, compile-time
        const int off = (cix & 7) * 64;
        const int u0 = (cix < 8) ? cur0 : nxt0;
        pa0 = *(const float4*)(emb + u0 + off + g0 * 8);
        const int u1 = (cix < 8) ? cur1 : nxt1;
        pa1 = *(const float4*)(emb + u1 + off + g0 * 8);
        if (has2) {
          const int u2 = (cix < 8) ? cur2 : nxt2;
          pa2 = *(const float4*)(emb + u2 + off + g0 * 8);
        }
      }
      // (d) frag reads + MFMA for chunk kc (buffer kc&3, published last body)
      const unsigned char* Ab = &As[kc & 3][0];
      #pragma unroll
      for (int ks = 0; ks < 2; ++ks) {
        const int sx = r * 64 + (((ks * 4 + q) ^ (r >> 1)) * 8);
        long long a[5];
        #pragma unroll
        for (int mt = 0; mt < 5; ++mt)
          a[mt] = *(const long long*)(Ab + mt * 1024 + sx);
        #pragma unroll
        for (int mt = 0; mt < 5; ++mt)
          #pragma unroll
          for (int t = 0; t < 2; ++t)
            acc[mt][t] = __builtin_amdgcn_mfma_f32_16x16x32_fp8_fp8(
                a[mt], barr[t][kc * 2 + ks], acc[mt][t], 0, 0, 0);
      }
      // (e) issue b-half loads chunk kc+3
      if (kc < 7) {
        const int cix = kc + 3;
        const int off = (cix & 7) * 64 + 4;
        const int u0 = (cix < 8) ? cur0 : nxt0;
        pb0 = *(const float4*)(emb + u0 + off + g0 * 8);
        const int u1 = (cix < 8) ? cur1 : nxt1;
        pb1 = *(const float4*)(emb + u1 + off + g0 * 8);
        if (has2) {
          const int u2 = (cix < 8) ? cur2 : nxt2;
          pb2 = *(const float4*)(emb + u2 + off + g0 * 8);
        }
      }
      // (f) publish store(kc+1); retire reads(kc). Buffer of kc rewritten at
      //     body kc+3 -> 3 barriers of separation.
      pub_barrier();
    }

    // ---- epilogue: pure lane-local scan (only pk + acc live) ---------------
    {
      float hn1 = 0.f, a2 = 1.f, b2 = 0.f;
      #pragma unroll
      for (int s = 0; s < 20; ++s) {
        const float yh = acc[s >> 2][0][s & 3] + bias2[0];
        const float yz = acc[s >> 2][1][s & 3] + bias2[1];
        const float z = sigm(yz);
        hn1 += z * (yh - hn1);     // layer-1 direct scan (valid on ly==0 lanes)
        a2 *= (1.f - z);           // layer-2 affine (valid on ly==1 lanes)
        b2 += z * (yh - b2);
      }
      const float u2 = __shfl_xor(hn1, 1);    // ly1 lane gets ly0's hn1
      if (ly == 1) hout[ng & 1][q][8 * w + (r >> 1)] = f2bf(a2 * u2 + b2);
    }
    pub_barrier();
    // packed store: 16 threads write 4 nodes x 64B (4 x dwordx4, same line)
    if (tid < 16) {
      const int nd = tid >> 2, seg = tid & 3;
      int4 v = *(const int4*)&hout[ng & 1][nd][seg * 8];
      *(int4*)(hnb + (long)(ng * 4 + nd) * 1024 + c0 + seg * 8) = v;
    }
    cur0 = nxt0; cur1 = nxt1; cur2 = nxt2;
    // post-epilogue: issue chunk 2 of the (new) current ng -> pa/pb.
    // Covered by the epilogue tail + next body-0 store before its cvt.
    {
      const float* s0 = emb + cur0 + 128 + g0 * 8;
      pa0 = *(const float4*)s0; pb0 = *(const float4*)(s0 + 4);
      const float* s1 = emb + cur1 + 128 + g0 * 8;
      pa1 = *(const float4*)s1; pb1 = *(const float4*)(s1 + 4);
      if (has2) {
        const float* s2 = emb + cur2 + 128 + g0 * 8;
        pa2 = *(const float4*)s2; pb2 = *(const float4*)(s2 + 4);
      }
    }
  }
}

// ------- score slot (raw sigmoid) = sigmoid(hn . lin_w + lin_b) -------------
__global__ void score_kernel(const unsigned short* __restrict__ hnb,
                             const float* __restrict__ lin_w,
                             const float* __restrict__ lin_b,
                             float* __restrict__ R) {
  int tid = threadIdx.x;
  int wv = tid >> 6, lane = tid & 63;
  int node = blockIdx.x * 4 + wv;
  int k = lane * 8;
  int4 hv = *(const int4*)(hnb + (long)node * 1024 + k);
  float4 w0 = *(const float4*)(lin_w + k);
  float4 w1 = *(const float4*)(lin_w + k + 4);
  float s = bflo(hv.x) * w0.x + bfhi(hv.x) * w0.y + bflo(hv.y) * w0.z + bfhi(hv.y) * w0.w
          + bflo(hv.z) * w1.x + bfhi(hv.z) * w1.y + bflo(hv.w) * w1.z + bfhi(hv.w) * w1.w;
  #pragma unroll
  for (int off = 32; off > 0; off >>= 1) s += __shfl_down(s, off);
  if (lane == 0) R[256 + (long)node * 512] = sigm(s + lin_b[0]);
}

// ---------------- pred[e] = score[src] * score[dst] -------------------------
__global__ void pred_kernel(const int* __restrict__ eli, const float* __restrict__ R,
                            float* __restrict__ out) {
  int e = blockIdx.x * 256 + threadIdx.x;
  if (e < EE) {
    int a = eli[e];       a = (unsigned)a < NN ? a : 0;
    int b = eli[EE + e];  b = (unsigned)b < NN ? b : 0;
    out[e] = R[256 + (long)a * 512] * R[256 + (long)b * 512];
  }
}

// ---------------- out2 = hn @ skip_w.T + skip_b (in-place-safe MFMA) --------
__launch_bounds__(256)
__global__ void out2_kernel(const unsigned short* __restrict__ hnb,
                            const float* __restrict__ skip_w,
                            const float* __restrict__ skip_b,
                            float* __restrict__ out2) {
  __shared__ unsigned short Asl[32][520];
  __shared__ unsigned short Bsl[512][40];
  const int tid = threadIdx.x;
  const int lane = tid & 63, wv = tid >> 6;
  const int r = lane & 15, q = lane >> 4;
  const int m0 = blockIdx.x * 32;

  {
    int arow = tid >> 4;
    int acol = (tid & 15) * 32;
    #pragma unroll
    for (int hh = 0; hh < 2; ++hh) {
      int grow = m0 + hh * 16 + arow;
      unsigned short* dst = &Asl[hh * 16 + arow][acol];
      if (grow < NN) {
        const unsigned short* hr = hnb + (long)grow * 1024 + acol;
        *(int4*)(dst)      = *(const int4*)(hr);
        *(int4*)(dst + 8)  = *(const int4*)(hr + 8);
        *(int4*)(dst + 16) = *(const int4*)(hr + 16);
        *(int4*)(dst + 24) = *(const int4*)(hr + 24);
      } else {
        int4 z = {0, 0, 0, 0};
        *(int4*)(dst) = z; *(int4*)(dst + 8) = z;
        *(int4*)(dst + 16) = z; *(int4*)(dst + 24) = z;
      }
    }
  }

  const f32x4 fzero = {0.f, 0.f, 0.f, 0.f};
  f32x4 acc[2][8];
  #pragma unroll
  for (int rg = 0; rg < 2; ++rg)
    #pragma unroll
    for (int i = 0; i < 8; ++i) acc[rg][i] = fzero;

  const int ksub = (tid & 3) * 8;
  const int jb = tid >> 2;

  for (int k0 = 0; k0 < H; k0 += 32) {
    __syncthreads();
    #pragma unroll
    for (int it = 0; it < 8; ++it) {
      int jj = it * 64 + jb;
      const float* src = skip_w + (long)jj * H + k0 + ksub;
      cvt_store8(&Bsl[jj][ksub], *(const float4*)src, *(const float4*)(src + 4));
    }
    __syncthreads();
    bf16x8 af0 = *(const bf16x8*)&Asl[r][k0 + q * 8];
    bf16x8 af1 = *(const bf16x8*)&Asl[16 + r][k0 + q * 8];
    #pragma unroll
    for (int i = 0; i < 8; ++i) {
      bf16x8 bf = *(const bf16x8*)&Bsl[(wv * 8 + i) * 16 + r][q * 8];
      acc[0][i] = __builtin_amdgcn_mfma_f32_16x16x32_bf16(af0, bf, acc[0][i], 0, 0, 0);
      acc[1][i] = __builtin_amdgcn_mfma_f32_16x16x32_bf16(af1, bf, acc[1][i], 0, 0, 0);
    }
  }
  #pragma unroll
  for (int rg = 0; rg < 2; ++rg)
    #pragma unroll
    for (int i = 0; i < 8; ++i) {
      int col = (wv * 8 + i) * 16 + r;
      float sbv = skip_b[col];
      #pragma unroll
      for (int g = 0; g < 4; ++g) {
        int grow = m0 + rg * 16 + q * 4 + g;
        if (grow < NN) out2[(long)grow * H + col] = acc[rg][i][g] + sbv;
      }
    }
}

// ---------------- host launcher (d_ws is UNUSABLE in this harness) ----------
extern "C" void kernel_launch(void* const* d_in, const int* in_sizes, int n_in,
                              void* d_out, int out_size, void* d_ws, size_t ws_size,
                              hipStream_t stream) {
  const float* emb    = (const float*)d_in[0];
  const float* W_ir   = (const float*)d_in[1];
  const float* b_ir   = (const float*)d_in[2];
  const float* W_iz   = (const float*)d_in[3];
  const float* b_iz   = (const float*)d_in[4];
  const float* lin_w  = (const float*)d_in[5];
  const float* lin_b  = (const float*)d_in[6];
  const float* skip_w = (const float*)d_in[7];
  const float* skip_b = (const float*)d_in[8];
  const int*   walk   = (const int*)d_in[9];
  const int*   eli    = (const int*)d_in[10];
  float* out = (float*)d_out;
  float* R   = out + EE;                           // out2 region: NN x H f32
  unsigned short* hnb = (unsigned short*)R;        // bf16 hn inside out2 slots

  dim3 g1(16, 48);
  gru_fused<<<g1, 256, 0, stream>>>(emb, W_ir, W_iz, b_ir, b_iz, walk, hnb);
  score_kernel<<<2500, 256, 0, stream>>>(hnb, lin_w, lin_b, R);
  pred_kernel<<<391, 256, 0, stream>>>(eli, R, out);        // before out2 (slots reused)
  out2_kernel<<<313, 256, 0, stream>>>(hnb, skip_w, skip_b, R);
}

// Round 12
// 654.627 us; speedup vs baseline: 1.2072x; 1.2072x over previous
//
#include <hip/hip_runtime.h>

#define H  512
#define NN 10000
#define SS 20
#define VV 100000
#define EE 100000

typedef __bf16 bf16x8 __attribute__((ext_vector_type(8)));
typedef float  f32x4  __attribute__((ext_vector_type(4)));

__device__ __forceinline__ unsigned short f2bf(float f) {
  unsigned u = __builtin_bit_cast(unsigned, f);
  u += 0x7FFFu + ((u >> 16) & 1u);
  return (unsigned short)(u >> 16);
}
__device__ __forceinline__ float bflo(int x) {
  return __builtin_bit_cast(float, (unsigned)x << 16);
}
__device__ __forceinline__ float bfhi(int x) {
  return __builtin_bit_cast(float, (unsigned)x & 0xFFFF0000u);
}
__device__ __forceinline__ float sigm(float x) { return 1.f / (1.f + __expf(-x)); }

// bf16 packing (kept for out2_kernel staging)
__device__ __forceinline__ unsigned cpk(float lo, float hi) {
  unsigned r;
  asm("v_cvt_pk_bf16_f32 %0, %1, %2" : "=v"(r) : "v"(lo), "v"(hi));
  return r;
}
__device__ __forceinline__ void cvt_store8(unsigned short* dst, float4 a, float4 b) {
  int4 v;
  v.x = (int)cpk(a.x, a.y); v.y = (int)cpk(a.z, a.w);
  v.z = (int)cpk(b.x, b.y); v.w = (int)cpk(b.z, b.w);
  *(int4*)dst = v;
}

// 8 f32 -> 8 fp8 (OCP e4m3 on gfx950) packed in a uint2 (4 VALU ops).
__device__ __forceinline__ uint2 cvt8_fp8(float4 a, float4 b) {
  int x = __builtin_amdgcn_cvt_pk_fp8_f32(a.x, a.y, 0, false);
  x = __builtin_amdgcn_cvt_pk_fp8_f32(a.z, a.w, x, true);
  int y = __builtin_amdgcn_cvt_pk_fp8_f32(b.x, b.y, 0, false);
  y = __builtin_amdgcn_cvt_pk_fp8_f32(b.z, b.w, y, true);
  uint2 r; r.x = (unsigned)x; r.y = (unsigned)y; return r;
}

// non-draining barrier: publish LDS writes, do NOT drain vmcnt (in-flight
// global loads legally span the barrier).
__device__ __forceinline__ void pub_barrier() {
  asm volatile("s_waitcnt lgkmcnt(0)\n\ts_barrier" ::: "memory");
}

// ---------------- fused gather + GEMM + GRU scan (persistent-B, fp8) --------
// R12 = R10 (best verified: 599us gru / 657 total) + direct hn stores.
// R10: conflict-free fp8 swizzle f(ar)=(ar>>1)&7 (1.7e8 -> 0 conflicts,
// quarter-wave bank model verified), 3 waves/SIMD via fp8 barr=64 VGPR.
// R11 (early-cvt packed state) REGRESSED (FETCH +360MB: in-loop state grew
// 24->30 regs, spill moved into the kc loop) -> reverted.
// R12 tweak: ly==1 lanes hold 8 CONSECUTIVE channels per node (r odd ->
// cch = c0+8w+(r>>1)) -> store f2bf ushort directly to hnb; removes the
// hout LDS round-trip + one barrier per ng. Zero register delta.
// Pipeline (R10): depth-1, 4 buffers, barrier every body:
//   body(kc): store(kc+1) ; issue a(kc+2) ; ds_read+MFMA(kc) ; issue b(kc+2)
// Grid 16cg x 48sb = 768 = 3/CU, __launch_bounds__(256,3).
// XCD swizzle (bijective, all 16 cg of an sb on one XCD): hwid = by*16+bx;
// j = hwid>>3; cg = j&15, sb = (hwid&7)*6 + (j>>4).
__launch_bounds__(256, 3)
__global__ void gru_fused(const float* __restrict__ emb,
                          const float* __restrict__ W_ir,
                          const float* __restrict__ W_iz,
                          const float* __restrict__ b_ir,
                          const float* __restrict__ b_iz,
                          const int* __restrict__ walk,
                          unsigned short* __restrict__ hnb) {
  __shared__ __align__(16) unsigned char As[4][80 * 64];  // fp8 tiles, 64B rows

  const int tid = threadIdx.x;
  const int w = tid >> 6, lane = tid & 63;
  const int r = lane & 15, q = lane >> 4;

  // XCD-aware remap (see header comment)
  const int hwid = blockIdx.y * 16 + blockIdx.x;
  const int j = hwid >> 3;
  const int cg = j & 15;
  const int sb = (hwid & 7) * 6 + (j >> 4);
  const int c0 = cg * 32;

  // ---- persistent B fragments: 2 tiles x 16 k-steps x 8 fp8 = 64 VGPRs ----
  const int ly = r & 1;                       // layer of this lane's columns
  const int cch = c0 + 8 * w + (r >> 1);      // channel of this lane's columns
  long long barr[2][16];
  float bias2[2];
  #pragma unroll
  for (int t = 0; t < 2; ++t) {               // t: 0 = h (W_ir), 1 = z (W_iz)
    const float* wrow = (t ? W_iz : W_ir) + (long)ly * H * H + (long)cch * H;
    #pragma unroll
    for (int u = 0; u < 16; ++u) {
      const float* s = wrow + u * 32 + q * 8;
      uint2 v = cvt8_fp8(*(const float4*)s, *(const float4*)(s + 4));
      barr[t][u] = __builtin_bit_cast(long long, v);
    }
    bias2[t] = (t ? b_iz : b_ir)[ly * H + cch];
  }

  // ---- A staging roles: thread -> rows {row0, +32, +64 (tid<128)} ----------
  // LMAP(m)=20*((m>>2)&3)+4*(m>>4)+(m&3): LMAP(m+32)=+8, LMAP(m+64)=+16.
  // SWZ(m)=m*64+((g0^((m>>1)&7))*8):      SWZ(m+32)=+2048, SWZ(m+64)=+4096.
  const int row0 = tid >> 3, g0 = tid & 7;
  const bool has2 = (tid < 128);              // wave-uniform (waves 0,1)
  const int L0 = 20 * ((row0 >> 2) & 3) + 4 * (row0 >> 4) + (row0 & 3);
  const int sw0 = row0 * 64 + ((g0 ^ ((row0 >> 1) & 7)) * 8);

  const int ngA = (2500 * sb) / 48;
  const int ngB = (2500 * (sb + 1)) / 48;

  int cur0, cur1, cur2;
  {
    const int* wp = walk + ngA * 80 + L0;
    int v0 = wp[0];  v0 = ((unsigned)v0 < VV) ? v0 : 0;
    int v1 = wp[8];  v1 = ((unsigned)v1 < VV) ? v1 : 0;
    int v2 = has2 ? wp[16] : 0; v2 = ((unsigned)v2 < VV) ? v2 : 0;
    cur0 = v0 * H; cur1 = v1 * H; cur2 = v2 * H;
  }

  // pf regs: a-half (pa*) lives through MFMA; b-half (pb*) issued after it
  float4 pa0, pb0, pa1, pb1, pa2 = {0,0,0,0}, pb2 = {0,0,0,0};

  // ---- prologue: stage chunk 0; issue chunk-1 loads ------------------------
  {
    const float* s0 = emb + cur0 + g0 * 8;
    const float* s1 = emb + cur1 + g0 * 8;
    const float* s2 = emb + cur2 + g0 * 8;
    float4 a0 = *(const float4*)s0, b0 = *(const float4*)(s0 + 4);
    float4 a1 = *(const float4*)s1, b1 = *(const float4*)(s1 + 4);
    float4 a2 = {0,0,0,0}, b2 = {0,0,0,0};
    if (has2) { a2 = *(const float4*)s2; b2 = *(const float4*)(s2 + 4); }
    *(uint2*)(&As[0][0] + sw0)        = cvt8_fp8(a0, b0);
    *(uint2*)(&As[0][0] + sw0 + 2048) = cvt8_fp8(a1, b1);
    if (has2) *(uint2*)(&As[0][0] + sw0 + 4096) = cvt8_fp8(a2, b2);
    // issue chunk 1
    pa0 = *(const float4*)(s0 + 64); pb0 = *(const float4*)(s0 + 68);
    pa1 = *(const float4*)(s1 + 64); pb1 = *(const float4*)(s1 + 68);
    if (has2) { pa2 = *(const float4*)(s2 + 64); pb2 = *(const float4*)(s2 + 68); }
  }
  pub_barrier();

  f32x4 acc[5][2];
  const f32x4 fz = {0.f, 0.f, 0.f, 0.f};

  for (int ng = ngA; ng < ngB; ++ng) {
    #pragma unroll
    for (int mt = 0; mt < 5; ++mt)
      #pragma unroll
      for (int t = 0; t < 2; ++t) acc[mt][t] = fz;

    const int ngn = (ng + 1 < ngB) ? ng + 1 : ng;   // clamped walk prefetch
    int nxt0, nxt1, nxt2;
    {
      const int* wp = walk + ngn * 80 + L0;
      int n0 = wp[0];  n0 = ((unsigned)n0 < VV) ? n0 : 0;
      int n1 = wp[8];  n1 = ((unsigned)n1 < VV) ? n1 : 0;
      int n2 = has2 ? wp[16] : 0; n2 = ((unsigned)n2 < VV) ? n2 : 0;
      nxt0 = n0 * H; nxt1 = n1 * H; nxt2 = n2 * H;
    }

    #pragma unroll
    for (int kc = 0; kc < 8; ++kc) {
      // (a) cvt+store chunk kc+1 (loads issued last body; auto-vmcnt)
      {
        unsigned char* An = &As[(kc + 1) & 3][0];
        *(uint2*)(An + sw0)        = cvt8_fp8(pa0, pb0);
        *(uint2*)(An + sw0 + 2048) = cvt8_fp8(pa1, pb1);
        if (has2) *(uint2*)(An + sw0 + 4096) = cvt8_fp8(pa2, pb2);
      }
      // (b) issue a-half loads for chunk kc+2
      {
        const int cix = kc + 2;                     // 2..9, compile-time
        const int off = (cix & 7) * 64;
        const int u0 = (cix < 8) ? cur0 : nxt0;
        pa0 = *(const float4*)(emb + u0 + off + g0 * 8);
        const int u1 = (cix < 8) ? cur1 : nxt1;
        pa1 = *(const float4*)(emb + u1 + off + g0 * 8);
        if (has2) {
          const int u2 = (cix < 8) ? cur2 : nxt2;
          pa2 = *(const float4*)(emb + u2 + off + g0 * 8);
        }
      }
      // (c) frag reads + MFMA for chunk kc (published by last body's barrier)
      const unsigned char* Ab = &As[kc & 3][0];
      #pragma unroll
      for (int ks = 0; ks < 2; ++ks) {
        const int sx = r * 64 + (((ks * 4 + q) ^ (r >> 1)) * 8);
        long long a[5];
        #pragma unroll
        for (int mt = 0; mt < 5; ++mt)
          a[mt] = *(const long long*)(Ab + mt * 1024 + sx);
        #pragma unroll
        for (int mt = 0; mt < 5; ++mt)
          #pragma unroll
          for (int t = 0; t < 2; ++t)
            acc[mt][t] = __builtin_amdgcn_mfma_f32_16x16x32_fp8_fp8(
                a[mt], barr[t][kc * 2 + ks], acc[mt][t], 0, 0, 0);
      }
      // (b2) issue b-half loads for chunk kc+2 (addresses recomputed from
      // live cur/nxt -> 12 fewer regs live through the MFMA section)
      {
        const int cix = kc + 2;
        const int off = (cix & 7) * 64 + 4;
        const int u0 = (cix < 8) ? cur0 : nxt0;
        pb0 = *(const float4*)(emb + u0 + off + g0 * 8);
        const int u1 = (cix < 8) ? cur1 : nxt1;
        pb1 = *(const float4*)(emb + u1 + off + g0 * 8);
        if (has2) {
          const int u2 = (cix < 8) ? cur2 : nxt2;
          pb2 = *(const float4*)(emb + u2 + off + g0 * 8);
        }
      }
      // (d) publish store(kc+1); retire reads(kc). Buffer of kc rewritten at
      //     body kc+3 -> 3 barriers of separation.
      pub_barrier();
    }

    // ---- epilogue: pure lane-local scan (h and z live in the same lane) ----
    // ly==1 lanes (r odd) hold 8 consecutive channels -> direct ushort store
    // to hnb (no LDS round-trip, no extra barrier).
    {
      float hn1 = 0.f, a2 = 1.f, b2 = 0.f;
      #pragma unroll
      for (int s = 0; s < 20; ++s) {
        const float yh = acc[s >> 2][0][s & 3] + bias2[0];
        const float yz = acc[s >> 2][1][s & 3] + bias2[1];
        const float z = sigm(yz);
        hn1 += z * (yh - hn1);     // layer-1 direct scan (valid on ly==0 lanes)
        a2 *= (1.f - z);           // layer-2 affine (valid on ly==1 lanes)
        b2 += z * (yh - b2);
      }
      const float u2 = __shfl_xor(hn1, 1);    // ly1 lane gets ly0's hn1
      if (ly == 1)
        hnb[(long)(ng * 4 + q) * 1024 + cch] = f2bf(a2 * u2 + b2);
    }
    cur0 = nxt0; cur1 = nxt1; cur2 = nxt2;
  }
}

// ------- score slot (raw sigmoid) = sigmoid(hn . lin_w + lin_b) -------------
__global__ void score_kernel(const unsigned short* __restrict__ hnb,
                             const float* __restrict__ lin_w,
                             const float* __restrict__ lin_b,
                             float* __restrict__ R) {
  int tid = threadIdx.x;
  int wv = tid >> 6, lane = tid & 63;
  int node = blockIdx.x * 4 + wv;
  int k = lane * 8;
  int4 hv = *(const int4*)(hnb + (long)node * 1024 + k);
  float4 w0 = *(const float4*)(lin_w + k);
  float4 w1 = *(const float4*)(lin_w + k + 4);
  float s = bflo(hv.x) * w0.x + bfhi(hv.x) * w0.y + bflo(hv.y) * w0.z + bfhi(hv.y) * w0.w
          + bflo(hv.z) * w1.x + bfhi(hv.z) * w1.y + bflo(hv.w) * w1.z + bfhi(hv.w) * w1.w;
  #pragma unroll
  for (int off = 32; off > 0; off >>= 1) s += __shfl_down(s, off);
  if (lane == 0) R[256 + (long)node * 512] = sigm(s + lin_b[0]);
}

// ---------------- pred[e] = score[src] * score[dst] -------------------------
__global__ void pred_kernel(const int* __restrict__ eli, const float* __restrict__ R,
                            float* __restrict__ out) {
  int e = blockIdx.x * 256 + threadIdx.x;
  if (e < EE) {
    int a = eli[e];       a = (unsigned)a < NN ? a : 0;
    int b = eli[EE + e];  b = (unsigned)b < NN ? b : 0;
    out[e] = R[256 + (long)a * 512] * R[256 + (long)b * 512];
  }
}

// ---------------- out2 = hn @ skip_w.T + skip_b (in-place-safe MFMA) --------
__launch_bounds__(256)
__global__ void out2_kernel(const unsigned short* __restrict__ hnb,
                            const float* __restrict__ skip_w,
                            const float* __restrict__ skip_b,
                            float* __restrict__ out2) {
  __shared__ unsigned short Asl[32][520];
  __shared__ unsigned short Bsl[512][40];
  const int tid = threadIdx.x;
  const int lane = tid & 63, wv = tid >> 6;
  const int r = lane & 15, q = lane >> 4;
  const int m0 = blockIdx.x * 32;

  {
    int arow = tid >> 4;
    int acol = (tid & 15) * 32;
    #pragma unroll
    for (int hh = 0; hh < 2; ++hh) {
      int grow = m0 + hh * 16 + arow;
      unsigned short* dst = &Asl[hh * 16 + arow][acol];
      if (grow < NN) {
        const unsigned short* hr = hnb + (long)grow * 1024 + acol;
        *(int4*)(dst)      = *(const int4*)(hr);
        *(int4*)(dst + 8)  = *(const int4*)(hr + 8);
        *(int4*)(dst + 16) = *(const int4*)(hr + 16);
        *(int4*)(dst + 24) = *(const int4*)(hr + 24);
      } else {
        int4 z = {0, 0, 0, 0};
        *(int4*)(dst) = z; *(int4*)(dst + 8) = z;
        *(int4*)(dst + 16) = z; *(int4*)(dst + 24) = z;
      }
    }
  }

  const f32x4 fzero = {0.f, 0.f, 0.f, 0.f};
  f32x4 acc[2][8];
  #pragma unroll
  for (int rg = 0; rg < 2; ++rg)
    #pragma unroll
    for (int i = 0; i < 8; ++i) acc[rg][i] = fzero;

  const int ksub = (tid & 3) * 8;
  const int jb = tid >> 2;

  for (int k0 = 0; k0 < H; k0 += 32) {
    __syncthreads();
    #pragma unroll
    for (int it = 0; it < 8; ++it) {
      int jj = it * 64 + jb;
      const float* src = skip_w + (long)jj * H + k0 + ksub;
      cvt_store8(&Bsl[jj][ksub], *(const float4*)src, *(const float4*)(src + 4));
    }
    __syncthreads();
    bf16x8 af0 = *(const bf16x8*)&Asl[r][k0 + q * 8];
    bf16x8 af1 = *(const bf16x8*)&Asl[16 + r][k0 + q * 8];
    #pragma unroll
    for (int i = 0; i < 8; ++i) {
      bf16x8 bf = *(const bf16x8*)&Bsl[(wv * 8 + i) * 16 + r][q * 8];
      acc[0][i] = __builtin_amdgcn_mfma_f32_16x16x32_bf16(af0, bf, acc[0][i], 0, 0, 0);
      acc[1][i] = __builtin_amdgcn_mfma_f32_16x16x32_bf16(af1, bf, acc[1][i], 0, 0, 0);
    }
  }
  #pragma unroll
  for (int rg = 0; rg < 2; ++rg)
    #pragma unroll
    for (int i = 0; i < 8; ++i) {
      int col = (wv * 8 + i) * 16 + r;
      float sbv = skip_b[col];
      #pragma unroll
      for (int g = 0; g < 4; ++g) {
        int grow = m0 + rg * 16 + q * 4 + g;
        if (grow < NN) out2[(long)grow * H + col] = acc[rg][i][g] + sbv;
      }
    }
}

// ---------------- host launcher (d_ws is UNUSABLE in this harness) ----------
extern "C" void kernel_launch(void* const* d_in, const int* in_sizes, int n_in,
                              void* d_out, int out_size, void* d_ws, size_t ws_size,
                              hipStream_t stream) {
  const float* emb    = (const float*)d_in[0];
  const float* W_ir   = (const float*)d_in[1];
  const float* b_ir   = (const float*)d_in[2];
  const float* W_iz   = (const float*)d_in[3];
  const float* b_iz   = (const float*)d_in[4];
  const float* lin_w  = (const float*)d_in[5];
  const float* lin_b  = (const float*)d_in[6];
  const float* skip_w = (const float*)d_in[7];
  const float* skip_b = (const float*)d_in[8];
  const int*   walk   = (const int*)d_in[9];
  const int*   eli    = (const int*)d_in[10];
  float* out = (float*)d_out;
  float* R   = out + EE;                           // out2 region: NN x H f32
  unsigned short* hnb = (unsigned short*)R;        // bf16 hn inside out2 slots

  dim3 g1(16, 48);
  gru_fused<<<g1, 256, 0, stream>>>(emb, W_ir, W_iz, b_ir, b_iz, walk, hnb);
  score_kernel<<<2500, 256, 0, stream>>>(hnb, lin_w, lin_b, R);
  pred_kernel<<<391, 256, 0, stream>>>(eli, R, out);        // before out2 (slots reused)
  out2_kernel<<<313, 256, 0, stream>>>(hnb, skip_w, skip_b, R);
}